// Round 2
// baseline (416.125 us; speedup 1.0000x reference)
//
#include <hip/hip_runtime.h>
#include <hip/hip_fp16.h>

#define HH 512
#define WW 512
#define NCH 3
#define NBATCH 16
#define NIMG (NBATCH*NCH)     // 48
#define CHUNK 32              // output rows per wave
#define NCHUNK (HH/CHUNK)     // 16
#define NSTRIP 4              // 128-col strips
#define SW 128
#define NT 64                 // one wave per block -> no barriers anywhere
#define NROWS (CHUNK+10)      // 42 input rows per wave
#define BLKS_PER_B (NCH*NCHUNK*NSTRIP)   // 192 partial slots per batch elem
#define NPAIR 70              // pair slots: cols c0-6 .. c0+133, 2 cols/slot

struct RowData { float4 m; float4 h; };
union RingQ { float4 f; __half2 h[4]; };

// R9: break the per-iteration LDS serial chain (R8 post-mortem: conflicts were
// NOT on the critical path; the stage-write -> in-order-LDS -> tap-read ->
// waitcnt chain was).
//  (a) Row staging double-buffered: iter it reads taps from buf[it&1]
//      (written LAST iter, already complete) and stages row it+1 into the
//      other buffer. Tap waitcnt no longer waits on same-iter writes.
//  (b) fp16 ring moved LDS -> registers (all slot indices compile-time in the
//      unrolled loops). Removes 2 LDS ops/iter; LDS 12800B -> 2240B.
// Arithmetic is bit-identical to R7/R8 (same fp16 round-trip), absmax 0.0.
// __launch_bounds__(64,3) caps VGPR at <=170 so 12 waves/CU is preserved.
__global__ __launch_bounds__(NT, 3) void ssim_main(
    const float* __restrict__ pred, const float* __restrict__ targ,
    float* __restrict__ ws)
{
  // pair-major float4 slots (slot k = cols c0-6+2k, c0-5+2k as x0,y0,x1,y1),
  // two row buffers alternating; all 70 slots rewritten every iteration; no
  // barriers (single wave, in-order LDS — validated R2-R8, absmax 0.0)
  __shared__ __align__(16) float4 rowp[2][NPAIR];

  const int l = threadIdx.x;
  const int blk = blockIdx.x;
  const int img = blk >> 6;              // / (NCHUNK*NSTRIP)
  const int rem = blk & 63;
  const int chunk = rem >> 2;
  const int strip = rem & 3;

  const int r0 = chunk*CHUNK - 5;        // first input row
  const int c0 = strip*SW;

  const size_t ib = (size_t)img * (size_t)(HH*WW);
  const float* pp = pred + ib;
  const float* tp = targ + ib;

  const int cm = c0 + 2*l;               // this lane's 2 main cols

  // halo duty: lanes 58..63 own pair slots {0,1,2, 67,68,69}
  const int hj = l - 58;                 // 0..5 on halo lanes, else negative
  const bool isH = (hj >= 0);
  const int hslot = (hj < 3) ? hj : (64 + hj);          // 0..2 / 67..69
  const int hcol  = (hj < 3) ? (c0 - 6 + 2*hj)          // left pair first col
                             : (c0 + 122 + 2*hj);       // right pair first col
  const bool hvalid = isH && ((hj < 3) ? (c0 > 0) : (c0 < 384));

  auto loadrow = [&](int it) -> RowData {
    RowData d;
    const int r = r0 + it;
    if ((unsigned)r < (unsigned)HH) {    // wave-uniform branch
      const size_t ro = (size_t)r * WW;
      const float2 x = *(const float2*)(pp + ro + cm);
      const float2 y = *(const float2*)(tp + ro + cm);
      d.m = make_float4(x.x, x.y, y.x, y.y);
      if (hvalid) {
        const float2 hx = *(const float2*)(pp + ro + hcol);
        const float2 hy = *(const float2*)(tp + ro + hcol);
        d.h = make_float4(hx.x, hx.y, hy.x, hy.y);
      } else {
        d.h = make_float4(0.f, 0.f, 0.f, 0.f);
      }
    } else {
      d.m = make_float4(0.f, 0.f, 0.f, 0.f);
      d.h = make_float4(0.f, 0.f, 0.f, 0.f);
    }
    return d;
  };

  auto stage = [&](int b, const RowData& d) {
    rowp[b][3 + l] = make_float4(d.m.x, d.m.z, d.m.y, d.m.w);
    if (isH) rowp[b][hslot] = make_float4(d.h.x, d.h.z, d.h.y, d.h.w);
  };

  // fp16 ring of horizontal sums — REGISTERS (static slot indices only)
  RingQ ringr[11];

  // vertical running sums: (x, y, xy, ss=xx+yy) per col — registers
  float2 vx = make_float2(0.f,0.f), vy = vx, vxy = vx, vss = vx;
  float acc = 0.f;

  // prologue: stage row 0 into buf 0, then 3-deep global prefetch (rows 1..3)
  {
    RowData row0d = loadrow(0);
    stage(0, row0d);
  }
  RowData cur = loadrow(1);
  RowData nxt = loadrow(2);
  RowData nx2 = loadrow(3);

  constexpr float c1 = 0.0001f, c2 = 0.0009f, inv121 = 1.0f/121.0f;

  auto ssim1 = [&](float Sx, float Sy, float Sxy, float Sss) -> float {
    const float mux = Sx*inv121, muy = Sy*inv121;
    const float muxy = mux*muy;
    const float m2   = fmaf(mux, mux, muy*muy);
    const float sgxy = fmaf(Sxy, inv121, -muxy);
    const float sgss = fmaf(Sss, inv121, -m2);
    const float num = fmaf(2.f, muxy, c1) * fmaf(2.f, sgxy, c2);
    const float den = (m2 + c1) * (sgss + c2);
    const float s = num * __builtin_amdgcn_rcpf(den);
    return fminf(fmaxf(s, 0.f), 1.f);
  };

  auto body = [&](int it, int slot, bool dosub, bool doemit) {
    const int b = it & 1;

    // tap reads FIRST: buf[b] was staged last iteration -> its write has long
    // completed; in-order LDS means these reads wait on nothing fresh.
    // pair slots l..l+6 cover cols 2l-6 .. 2l+7; taps p0..p11 = cols 2l-5..2l+6
    const float4* tb = rowp[b] + l;
    float4 v[7];
    #pragma unroll
    for (int j = 0; j < 7; ++j) v[j] = tb[j];

    // stage NEXT row into the other buffer; its completion only matters at the
    // next iteration's tap reads -> fully hidden under this iter's compute
    stage(b ^ 1, cur);
    cur = nxt; nxt = nx2;
    nx2 = loadrow(it + 4);               // global prefetch 3 rows ahead

    float sx=0.f, sy=0.f, sxy=0.f, sss=0.f;
    float x0=0.f, y0=0.f, x11=0.f, y11=0.f;
    #pragma unroll
    for (int j = 0; j < 6; ++j) {
      // identical arithmetic sequence to R7: tv = (x[p],y[p],x[p+1],y[p+1]), p=2j
      const float4 tv = make_float4(v[j].z, v[j].w, v[j+1].x, v[j+1].y);
      if (j == 0) { x0 = tv.x; y0 = tv.y; }
      sx += tv.x; sy += tv.y;
      sxy = fmaf(tv.x, tv.y, sxy);
      sss = fmaf(tv.x, tv.x, sss);
      sss = fmaf(tv.y, tv.y, sss);
      if (j < 5) {
        sx += tv.z; sy += tv.w;
        sxy = fmaf(tv.z, tv.w, sxy);
        sss = fmaf(tv.z, tv.z, sss);
        sss = fmaf(tv.w, tv.w, sss);
      } else { x11 = tv.z; y11 = tv.w; }
    }

    // col0 window = p0..p10 ; col1 = col0 - p0 + p11
    const float2 hx  = make_float2(sx,  sx - x0 + x11);
    const float2 hy  = make_float2(sy,  sy - y0 + y11);
    const float2 hxy = make_float2(sxy, fmaf(x11, y11, fmaf(-x0, y0, sxy)));
    const float2 hss = make_float2(sss,
        fmaf(x11, x11, fmaf(y11, y11, fmaf(-x0, x0, fmaf(-y0, y0, sss)))));

    // ring-old from registers
    RingQ ou;
    if (dosub) ou = ringr[slot];

    // round h to fp16 once; add the rounded value and store the identical
    // rounded value -> later subtract cancels exactly (no drift)
    RingQ qu;
    qu.h[0] = __floats2half2_rn(hx.x,  hy.x);
    qu.h[1] = __floats2half2_rn(hxy.x, hss.x);
    qu.h[2] = __floats2half2_rn(hx.y,  hy.y);
    qu.h[3] = __floats2half2_rn(hxy.y, hss.y);
    ringr[slot] = qu;
    const float2 a0 = __half22float2(qu.h[0]), a1 = __half22float2(qu.h[1]);
    const float2 a2 = __half22float2(qu.h[2]), a3 = __half22float2(qu.h[3]);

    if (dosub) {
      const float2 oxy0 = __half22float2(ou.h[0]), ops0 = __half22float2(ou.h[1]);
      const float2 oxy1 = __half22float2(ou.h[2]), ops1 = __half22float2(ou.h[3]);
      vx.x  -= oxy0.x; vy.x  -= oxy0.y; vxy.x -= ops0.x; vss.x -= ops0.y;
      vx.y  -= oxy1.x; vy.y  -= oxy1.y; vxy.y -= ops1.x; vss.y -= ops1.y;
    }
    vx.x += a0.x; vy.x += a0.y; vxy.x += a1.x; vss.x += a1.y;
    vx.y += a2.x; vy.y += a2.y; vxy.y += a3.x; vss.y += a3.y;

    if (doemit) {
      acc += ssim1(vx.x, vy.x, vxy.x, vss.x);
      acc += ssim1(vx.y, vy.y, vxy.y, vss.y);
    }
  };

  // 42 input rows: warmup 11 (first emit at it=10), steady 2x11, tail 9
  #pragma unroll
  for (int u = 0; u < 11; ++u) body(u, u, false, u == 10);
  for (int g = 0; g < 2; ++g) {
    #pragma unroll
    for (int u = 0; u < 11; ++u) body(11 + 11*g + u, u, true, true);
  }
  #pragma unroll
  for (int u = 0; u < 9; ++u) body(33 + u, u, true, true);

  // wave reduction -> per-block partial slot (written unconditionally: no
  // memset of d_ws needed, no atomics)
  #pragma unroll
  for (int off = 32; off > 0; off >>= 1) acc += __shfl_down(acc, off, 64);
  if (l == 0) ws[blk] = acc;
}

__global__ void ssim_final(const float* __restrict__ ws, float* __restrict__ out) {
  const int b = blockIdx.x;              // batch element
  const int t = threadIdx.x;             // 64 threads
  const float* p = ws + b * BLKS_PER_B;
  float s = p[t] + p[t + 64] + p[t + 128];
  #pragma unroll
  for (int off = 32; off > 0; off >>= 1) s += __shfl_down(s, off, 64);
  if (t == 0) out[b] = 1.0f - s * (1.0f / (float)(NCH*HH*WW));
}

extern "C" void kernel_launch(void* const* d_in, const int* in_sizes, int n_in,
                              void* d_out, int out_size, void* d_ws, size_t ws_size,
                              hipStream_t stream) {
  const float* pred = (const float*)d_in[0];
  const float* targ = (const float*)d_in[1];
  float* out = (float*)d_out;
  float* ws  = (float*)d_ws;
  ssim_main<<<dim3(NIMG*NCHUNK*NSTRIP), dim3(NT), 0, stream>>>(pred, targ, ws);
  ssim_final<<<dim3(NBATCH), dim3(64), 0, stream>>>(ws, out);
}

// Round 3
// 145.949 us; speedup vs baseline: 2.8512x; 2.8512x over previous
//
#include <hip/hip_runtime.h>
#include <hip/hip_fp16.h>

#define HH 512
#define WW 512
#define NCH 3
#define NBATCH 16
#define NIMG (NBATCH*NCH)     // 48
#define CHUNK 32              // output rows per wave
#define NCHUNK (HH/CHUNK)     // 16
#define NSTRIP 4              // 128-col strips
#define SW 128
#define SLOTS 140             // cols c0-5 .. c0+132 at slot = col-c0+5
#define NT 64                 // one wave per block -> no barriers anywhere
#define NROWS (CHUNK+10)      // 42 input rows per wave
#define BLKS_PER_B (NCH*NCHUNK*NSTRIP)   // 192 partial slots per batch elem

struct RowData { float4 m; float2 h; };
union RingQ { float4 f; __half2 h[4]; };

// R10 = R7 (59us best) + row-staging DOUBLE-BUFFER only.
//  R8 taught: bank conflicts on the staging writes are NOT on the critical
//  path (removing them regressed). R9 taught: the ring must stay in LDS (the
//  union array went to scratch: WRITE_SIZE 98KB->601MB, 5x slowdown).
//  Remaining theory: the same-iteration stage-write -> in-order-LDS ->
//  tap-read chain serializes each iteration. Fix: iter it reads taps from
//  rowb[it&1] (staged LAST iter, already complete) and stages row it+1 into
//  the other buffer. Everything else is bit-identical R7 (absmax 0.0).
__global__ __launch_bounds__(NT) void ssim_main(
    const float* __restrict__ pred, const float* __restrict__ targ,
    float* __restrict__ ws)
{
  // row staging, 2 buffers: slot s holds (x,y) of col c0+s-5 (same-wave LDS
  // is in-order; no barriers needed — validated R2-R8, absmax 0.0)
  __shared__ __align__(16) float2 rowb[2][SLOTS];
  // fp16 ring of horizontal sums: one 16B word per (slot,lane):
  // {c0:(hx,hy),(hxy,hss), c1:(hx,hy),(hxy,hss)} — read/write as b128
  __shared__ __align__(16) float4 ring[11][NT];

  const int l = threadIdx.x;
  const int blk = blockIdx.x;
  const int img = blk >> 6;              // / (NCHUNK*NSTRIP)
  const int rem = blk & 63;
  const int chunk = rem >> 2;
  const int strip = rem & 3;

  const int r0 = chunk*CHUNK - 5;        // first input row
  const int c0 = strip*SW;

  // zero the pad slots once in BOTH buffers (image-edge strips keep them zero)
  if (l < 10) {
    const int s = (l < 5) ? l : (128 + l);
    rowb[0][s] = make_float2(0.f, 0.f);
    rowb[1][s] = make_float2(0.f, 0.f);
  }

  const size_t ib = (size_t)img * (size_t)(HH*WW);
  const float* pp = pred + ib;
  const float* tp = targ + ib;

  const int cm = c0 + 2*l;               // this lane's 2 main cols
  const int h  = l - 54;                 // halo id 0..9 on lanes 54..63
  const int ch = (h < 5) ? (c0 - 5 + h) : (c0 + 123 + h);   // halo col
  const bool hval = (l >= 54) && ((unsigned)ch < (unsigned)WW);
  const int hs = (h < 5) ? h : (128 + h);                    // halo slot

  auto loadrow = [&](int it) -> RowData {
    RowData d;
    const int r = r0 + it;
    if ((unsigned)r < (unsigned)HH) {    // wave-uniform branch
      const size_t ro = (size_t)r * WW;
      const float2 x = *(const float2*)(pp + ro + cm);
      const float2 y = *(const float2*)(tp + ro + cm);
      d.m = make_float4(x.x, x.y, y.x, y.y);
      if (hval) d.h = make_float2(pp[ro + ch], tp[ro + ch]);
      else      d.h = make_float2(0.f, 0.f);
    } else {
      d.m = make_float4(0.f, 0.f, 0.f, 0.f);
      d.h = make_float2(0.f, 0.f);
    }
    return d;
  };

  auto stage = [&](int b, const RowData& d) {
    // interleaved (x,y) so taps read as aligned float4
    rowb[b][5 + 2*l] = make_float2(d.m.x, d.m.z);
    rowb[b][6 + 2*l] = make_float2(d.m.y, d.m.w);
    if (hval) rowb[b][hs] = d.h;
  };

  // vertical running sums: (x, y, xy, ss=xx+yy) per col — registers
  float2 vx = make_float2(0.f,0.f), vy = vx, vxy = vx, vss = vx;
  float acc = 0.f;

  // prologue: stage row 0 into buf 0, then 3-deep global prefetch (rows 1..3)
  {
    RowData row0d = loadrow(0);
    stage(0, row0d);
  }
  RowData cur = loadrow(1);
  RowData nxt = loadrow(2);
  RowData nx2 = loadrow(3);

  constexpr float c1 = 0.0001f, c2 = 0.0009f, inv121 = 1.0f/121.0f;

  auto ssim1 = [&](float Sx, float Sy, float Sxy, float Sss) -> float {
    const float mux = Sx*inv121, muy = Sy*inv121;
    const float muxy = mux*muy;
    const float m2   = fmaf(mux, mux, muy*muy);
    const float sgxy = fmaf(Sxy, inv121, -muxy);
    const float sgss = fmaf(Sss, inv121, -m2);
    const float num = fmaf(2.f, muxy, c1) * fmaf(2.f, sgxy, c2);
    const float den = (m2 + c1) * (sgss + c2);
    const float s = num * __builtin_amdgcn_rcpf(den);
    return fminf(fmaxf(s, 0.f), 1.f);
  };

  auto body = [&](int it, int slot, bool dosub, bool doemit) {
    const int b = it & 1;

    // tap reads FIRST, from the buffer staged LAST iteration: in-order LDS
    // means these wait on nothing issued this iteration.
    // taps p=0..11 <-> local cols 2l-5 .. 2l+6 <-> slots 2l .. 2l+11
    const float4* tb = (const float4*)(rowb[b] + 2*l);
    float4 tv[6];
    #pragma unroll
    for (int j = 0; j < 6; ++j) tv[j] = tb[j];

    // stage NEXT row into the other buffer; completion only matters at the
    // next iteration's tap reads -> hidden under this iteration's compute
    stage(b ^ 1, cur);
    cur = nxt; nxt = nx2;
    nx2 = loadrow(it + 4);               // global prefetch 3 rows ahead

    // ring-old read as ONE b128 (conflict-free 16B/lane pattern)
    RingQ ou;
    if (dosub) ou.f = ring[slot][l];

    float sx=0.f, sy=0.f, sxy=0.f, sss=0.f;
    float x0=0.f, y0=0.f, x11=0.f, y11=0.f;
    #pragma unroll
    for (int j = 0; j < 6; ++j) {
      const float4 v = tv[j];            // (x[p], y[p], x[p+1], y[p+1]), p=2j
      if (j == 0) { x0 = v.x; y0 = v.y; }
      sx += v.x; sy += v.y;
      sxy = fmaf(v.x, v.y, sxy);
      sss = fmaf(v.x, v.x, sss);
      sss = fmaf(v.y, v.y, sss);
      if (j < 5) {
        sx += v.z; sy += v.w;
        sxy = fmaf(v.z, v.w, sxy);
        sss = fmaf(v.z, v.z, sss);
        sss = fmaf(v.w, v.w, sss);
      } else { x11 = v.z; y11 = v.w; }
    }

    // col0 window = p0..p10 ; col1 = col0 - p0 + p11
    const float2 hx  = make_float2(sx,  sx - x0 + x11);
    const float2 hy  = make_float2(sy,  sy - y0 + y11);
    const float2 hxy = make_float2(sxy, fmaf(x11, y11, fmaf(-x0, y0, sxy)));
    const float2 hss = make_float2(sss,
        fmaf(x11, x11, fmaf(y11, y11, fmaf(-x0, x0, fmaf(-y0, y0, sss)))));

    // round h to fp16 once; add the rounded value and store the identical
    // rounded value -> later subtract cancels exactly (no drift)
    RingQ qu;
    qu.h[0] = __floats2half2_rn(hx.x,  hy.x);
    qu.h[1] = __floats2half2_rn(hxy.x, hss.x);
    qu.h[2] = __floats2half2_rn(hx.y,  hy.y);
    qu.h[3] = __floats2half2_rn(hxy.y, hss.y);
    ring[slot][l] = qu.f;                // ONE b128 write
    const float2 a0 = __half22float2(qu.h[0]), a1 = __half22float2(qu.h[1]);
    const float2 a2 = __half22float2(qu.h[2]), a3 = __half22float2(qu.h[3]);

    if (dosub) {
      const float2 oxy0 = __half22float2(ou.h[0]), ops0 = __half22float2(ou.h[1]);
      const float2 oxy1 = __half22float2(ou.h[2]), ops1 = __half22float2(ou.h[3]);
      vx.x  -= oxy0.x; vy.x  -= oxy0.y; vxy.x -= ops0.x; vss.x -= ops0.y;
      vx.y  -= oxy1.x; vy.y  -= oxy1.y; vxy.y -= ops1.x; vss.y -= ops1.y;
    }
    vx.x += a0.x; vy.x += a0.y; vxy.x += a1.x; vss.x += a1.y;
    vx.y += a2.x; vy.y += a2.y; vxy.y += a3.x; vss.y += a3.y;

    if (doemit) {
      acc += ssim1(vx.x, vy.x, vxy.x, vss.x);
      acc += ssim1(vx.y, vy.y, vxy.y, vss.y);
    }
  };

  // 42 input rows: warmup 11 (first emit at it=10), steady 2x11, tail 9
  #pragma unroll
  for (int u = 0; u < 11; ++u) body(u, u, false, u == 10);
  for (int g = 0; g < 2; ++g) {
    #pragma unroll
    for (int u = 0; u < 11; ++u) body(11 + 11*g + u, u, true, true);
  }
  #pragma unroll
  for (int u = 0; u < 9; ++u) body(33 + u, u, true, true);

  // wave reduction -> per-block partial slot (written unconditionally: no
  // memset of d_ws needed, no atomics)
  #pragma unroll
  for (int off = 32; off > 0; off >>= 1) acc += __shfl_down(acc, off, 64);
  if (l == 0) ws[blk] = acc;
}

__global__ void ssim_final(const float* __restrict__ ws, float* __restrict__ out) {
  const int b = blockIdx.x;              // batch element
  const int t = threadIdx.x;             // 64 threads
  const float* p = ws + b * BLKS_PER_B;
  float s = p[t] + p[t + 64] + p[t + 128];
  #pragma unroll
  for (int off = 32; off > 0; off >>= 1) s += __shfl_down(s, off, 64);
  if (t == 0) out[b] = 1.0f - s * (1.0f / (float)(NCH*HH*WW));
}

extern "C" void kernel_launch(void* const* d_in, const int* in_sizes, int n_in,
                              void* d_out, int out_size, void* d_ws, size_t ws_size,
                              hipStream_t stream) {
  const float* pred = (const float*)d_in[0];
  const float* targ = (const float*)d_in[1];
  float* out = (float*)d_out;
  float* ws  = (float*)d_ws;
  ssim_main<<<dim3(NIMG*NCHUNK*NSTRIP), dim3(NT), 0, stream>>>(pred, targ, ws);
  ssim_final<<<dim3(NBATCH), dim3(64), 0, stream>>>(ws, out);
}